// Round 3
// baseline (946.557 us; speedup 1.0000x reference)
//
#include <hip/hip_runtime.h>

#define NB 512
#define NC 32
#define NT 8192
#define TP 1024        // NT / 8 pooled windows
#define NG 11
#define WIN 256        // pooled windows per block (2048 time samples)
#define NTB (TP/WIN)   // 4 time-tiles per batch

typedef float f32x4 __attribute__((ext_vector_type(4)));

// One channel: 8 KB of x (nt) + 8 KB of W per wave, as 8+8 dwordx4 loads.
// DENSE lane mapping: load l, lane i covers bytes [1024*l + 16*i, +16) of the
// tile -> every 64-B line touched by exactly one instruction, 1 KB/instr.
// Lane i thus owns QUAD 64l+i (half of window 32l + i/2); pairing is deferred
// to the epilogue (shfl_xor(1)).
template<int C>
__device__ __forceinline__ void do_ch(const float* __restrict__ xb,
                                      const float* __restrict__ Wb,
                                      const float* __restrict__ bias,
                                      float (&acc)[8])
{
    f32x4 xv[8], wv[8];
    #pragma unroll
    for (int l = 0; l < 8; ++l)
        xv[l] = __builtin_nontemporal_load((const f32x4*)(xb + C * NT + 256 * l));
    #pragma unroll
    for (int l = 0; l < 8; ++l)
        wv[l] = *(const f32x4*)(Wb + C * NT + 256 * l);
    const float nbc = -bias[C];
    #pragma unroll
    for (int l = 0; l < 8; ++l) {
        const f32x4 a = xv[l], b = wv[l];
        float s;
        s  = fmaxf(fmaf(a.x, b.x, nbc), 0.0f);
        s += fmaxf(fmaf(a.y, b.y, nbc), 0.0f);
        s += fmaxf(fmaf(a.z, b.z, nbc), 0.0f);
        s += fmaxf(fmaf(a.w, b.w, nbc), 0.0f);
        acc[l] += s;
    }
}

// Pair-sum quads into windows and store. Lanes 2j,2j+1 hold the two quads of
// window 32l+j; after shfl_xor(1) both hold the window sum; even lanes store
// 32 consecutive dwords (128 B coalesced half-wave store).
__device__ __forceinline__ void store_g(float* __restrict__ ob, int gid,
                                        float inv, const float (&acc)[8], int lane)
{
    #pragma unroll
    for (int l = 0; l < 8; ++l) {
        const float s = acc[l] + __shfl_xor(acc[l], 1, 64);
        if (!(lane & 1))
            __builtin_nontemporal_store(s * inv,
                ob + (size_t)gid * TP + 32 * l + (lane >> 1));
    }
}

__global__ __launch_bounds__(256, 4) void local_gnn_kernel(
    const float* __restrict__ xg,
    const float* __restrict__ W,
    const float* __restrict__ bias,
    float* __restrict__ out)
{
    const int lane = threadIdx.x & 63;
    const int y    = threadIdx.x >> 6;   // wave id — wave-uniform
    const int bb   = blockIdx.x >> 2;    // batch
    const int tb   = blockIdx.x & 3;     // time-tile

    const float* xb = xg + (size_t)bb * (NC * NT) + tb * (WIN * 8) + 4 * lane;
    const float* Wb = W + tb * (WIN * 8) + 4 * lane;

    // acc[lg][l]: local group lg (<=3 per wave), quad-position l (8 per tile)
    float acc[3][8];
    #pragma unroll
    for (int lg = 0; lg < 3; ++lg)
        #pragma unroll
        for (int l = 0; l < 8; ++l) acc[lg][l] = 0.0f;

    float* ob = out + (size_t)bb * (NG * TP) + tb * WIN;

    // Each wave owns WHOLE groups -> no cross-wave reduction, no LDS, no
    // barrier. Channel counts per wave: 7 / 7 / 7 / 8.
    switch (y) {
    case 0:  // g0:{0,1}  g1:{3,2}  g6:{6,23,24}
        do_ch<0>(xb, Wb, bias, acc[0]);  do_ch<1>(xb, Wb, bias, acc[0]);
        do_ch<2>(xb, Wb, bias, acc[1]);  do_ch<3>(xb, Wb, bias, acc[1]);
        do_ch<6>(xb, Wb, bias, acc[2]);  do_ch<23>(xb, Wb, bias, acc[2]);
        do_ch<24>(xb, Wb, bias, acc[2]);
        store_g(ob, 0, 1.f/16, acc[0], lane);
        store_g(ob, 1, 1.f/16, acc[1], lane);
        store_g(ob, 6, 1.f/24, acc[2], lane);
        break;
    case 1:  // g2:{4,5}  g7:{8,9,27}  g9:{12,30}
        do_ch<4>(xb, Wb, bias, acc[0]);  do_ch<5>(xb, Wb, bias, acc[0]);
        do_ch<8>(xb, Wb, bias, acc[1]);  do_ch<9>(xb, Wb, bias, acc[1]);
        do_ch<27>(xb, Wb, bias, acc[1]);
        do_ch<12>(xb, Wb, bias, acc[2]); do_ch<30>(xb, Wb, bias, acc[2]);
        store_g(ob, 2, 1.f/16, acc[0], lane);
        store_g(ob, 7, 1.f/24, acc[1], lane);
        store_g(ob, 9, 1.f/16, acc[2], lane);
        break;
    case 2:  // g3:{16,17}  g4:{19,20}  g10:{13,14,31}
        do_ch<16>(xb, Wb, bias, acc[0]); do_ch<17>(xb, Wb, bias, acc[0]);
        do_ch<19>(xb, Wb, bias, acc[1]); do_ch<20>(xb, Wb, bias, acc[1]);
        do_ch<13>(xb, Wb, bias, acc[2]); do_ch<14>(xb, Wb, bias, acc[2]);
        do_ch<31>(xb, Wb, bias, acc[2]);
        store_g(ob, 3, 1.f/16, acc[0], lane);
        store_g(ob, 4, 1.f/16, acc[1], lane);
        store_g(ob, 10, 1.f/24, acc[2], lane);
        break;
    default: // g5:{22,21}  g8:{11,10,15,28,26,29}
        do_ch<21>(xb, Wb, bias, acc[0]); do_ch<22>(xb, Wb, bias, acc[0]);
        do_ch<10>(xb, Wb, bias, acc[1]); do_ch<11>(xb, Wb, bias, acc[1]);
        do_ch<15>(xb, Wb, bias, acc[1]); do_ch<26>(xb, Wb, bias, acc[1]);
        do_ch<28>(xb, Wb, bias, acc[1]); do_ch<29>(xb, Wb, bias, acc[1]);
        store_g(ob, 5, 1.f/16, acc[0], lane);
        store_g(ob, 8, 1.f/48, acc[1], lane);
        break;
    }
}

extern "C" void kernel_launch(void* const* d_in, const int* in_sizes, int n_in,
                              void* d_out, int out_size, void* d_ws, size_t ws_size,
                              hipStream_t stream) {
    const float* x    = (const float*)d_in[0];
    const float* W    = (const float*)d_in[1];
    const float* bias = (const float*)d_in[2];
    float* out        = (float*)d_out;

    const int grid = NB * NTB;   // 512 * 4 = 2048 blocks
    hipLaunchKernelGGL(local_gnn_kernel, dim3(grid), dim3(256), 0, stream,
                       x, W, bias, out);
}

// Round 4
// 785.943 us; speedup vs baseline: 1.2044x; 1.2044x over previous
//
#include <hip/hip_runtime.h>

#define NB 512
#define NC 32
#define NT 8192
#define TP 1024        // NT / 8 pooled windows
#define NG 11
#define WIN 128        // pooled windows per block (1024 samples, 4 KB/channel)
#define NTB (TP/WIN)   // 8 time-tiles per batch

typedef float f32x4 __attribute__((ext_vector_type(4)));

// One channel: 4 KB of x (nt) + 4 KB of W per wave, as 4+4 dwordx4 loads.
// DENSE lane mapping: load l, lane i covers bytes [1024*l + 16*i, +16) ->
// every 64-B line touched by exactly one instruction, 1 KB/instr.
// Transient register footprint: xv[4]+wv[4] = 32 VGPRs — sized so total
// demand stays under the 64-VGPR allocation the backend's occupancy
// heuristic picks (R3 post-mortem: 8-deep batches spilled 705 MB to scratch).
template<int C>
__device__ __forceinline__ void do_ch(const float* __restrict__ xb,
                                      const float* __restrict__ Wb,
                                      const float* __restrict__ bias,
                                      float (&acc)[4])
{
    f32x4 xv[4], wv[4];
    #pragma unroll
    for (int l = 0; l < 4; ++l)
        xv[l] = __builtin_nontemporal_load((const f32x4*)(xb + C * NT + 256 * l));
    #pragma unroll
    for (int l = 0; l < 4; ++l)
        wv[l] = *(const f32x4*)(Wb + C * NT + 256 * l);
    const float nbc = -bias[C];
    #pragma unroll
    for (int l = 0; l < 4; ++l) {
        const f32x4 a = xv[l], b = wv[l];
        float s;
        s  = fmaxf(fmaf(a.x, b.x, nbc), 0.0f);
        s += fmaxf(fmaf(a.y, b.y, nbc), 0.0f);
        s += fmaxf(fmaf(a.z, b.z, nbc), 0.0f);
        s += fmaxf(fmaf(a.w, b.w, nbc), 0.0f);
        acc[l] += s;
    }
}

// Lanes 2j,2j+1 hold the two quads of window 32l+j; after shfl_xor(1) both
// hold the window sum; even lanes store 32 consecutive dwords (128 B
// coalesced half-wave store, full-line, no write-allocate).
__device__ __forceinline__ void store_g(float* __restrict__ ob, int gid,
                                        float inv, const float (&acc)[4], int lane)
{
    #pragma unroll
    for (int l = 0; l < 4; ++l) {
        const float s = acc[l] + __shfl_xor(acc[l], 1, 64);
        if (!(lane & 1))
            __builtin_nontemporal_store(s * inv,
                ob + (size_t)gid * TP + 32 * l + (lane >> 1));
    }
}

__global__ __launch_bounds__(256, 4) void local_gnn_kernel(
    const float* __restrict__ xg,
    const float* __restrict__ W,
    const float* __restrict__ bias,
    float* __restrict__ out)
{
    const int lane = threadIdx.x & 63;
    const int y    = threadIdx.x >> 6;     // wave id — wave-uniform
    const int bb   = blockIdx.x >> 3;      // batch
    const int tb   = blockIdx.x & 7;       // time-tile

    const float* xb = xg + (size_t)bb * (NC * NT) + tb * (WIN * 8) + 4 * lane;
    const float* Wb = W + tb * (WIN * 8) + 4 * lane;

    // acc[lg][l]: local group lg (<=3 per wave), quad-position l (4 per tile)
    float acc[3][4];
    #pragma unroll
    for (int lg = 0; lg < 3; ++lg)
        #pragma unroll
        for (int l = 0; l < 4; ++l) acc[lg][l] = 0.0f;

    float* ob = out + (size_t)bb * (NG * TP) + tb * WIN;

    // Each wave owns WHOLE groups -> no cross-wave reduction, no LDS, no
    // barrier. Channel counts per wave: 7 / 7 / 7 / 8.
    switch (y) {
    case 0:  // g0:{0,1}  g1:{3,2}  g6:{6,23,24}
        do_ch<0>(xb, Wb, bias, acc[0]);  do_ch<1>(xb, Wb, bias, acc[0]);
        do_ch<2>(xb, Wb, bias, acc[1]);  do_ch<3>(xb, Wb, bias, acc[1]);
        do_ch<6>(xb, Wb, bias, acc[2]);  do_ch<23>(xb, Wb, bias, acc[2]);
        do_ch<24>(xb, Wb, bias, acc[2]);
        store_g(ob, 0, 1.f/16, acc[0], lane);
        store_g(ob, 1, 1.f/16, acc[1], lane);
        store_g(ob, 6, 1.f/24, acc[2], lane);
        break;
    case 1:  // g2:{4,5}  g7:{8,9,27}  g9:{12,30}
        do_ch<4>(xb, Wb, bias, acc[0]);  do_ch<5>(xb, Wb, bias, acc[0]);
        do_ch<8>(xb, Wb, bias, acc[1]);  do_ch<9>(xb, Wb, bias, acc[1]);
        do_ch<27>(xb, Wb, bias, acc[1]);
        do_ch<12>(xb, Wb, bias, acc[2]); do_ch<30>(xb, Wb, bias, acc[2]);
        store_g(ob, 2, 1.f/16, acc[0], lane);
        store_g(ob, 7, 1.f/24, acc[1], lane);
        store_g(ob, 9, 1.f/16, acc[2], lane);
        break;
    case 2:  // g3:{16,17}  g4:{19,20}  g10:{13,14,31}
        do_ch<16>(xb, Wb, bias, acc[0]); do_ch<17>(xb, Wb, bias, acc[0]);
        do_ch<19>(xb, Wb, bias, acc[1]); do_ch<20>(xb, Wb, bias, acc[1]);
        do_ch<13>(xb, Wb, bias, acc[2]); do_ch<14>(xb, Wb, bias, acc[2]);
        do_ch<31>(xb, Wb, bias, acc[2]);
        store_g(ob, 3, 1.f/16, acc[0], lane);
        store_g(ob, 4, 1.f/16, acc[1], lane);
        store_g(ob, 10, 1.f/24, acc[2], lane);
        break;
    default: // g5:{22,21}  g8:{11,10,15,28,26,29}
        do_ch<21>(xb, Wb, bias, acc[0]); do_ch<22>(xb, Wb, bias, acc[0]);
        do_ch<10>(xb, Wb, bias, acc[1]); do_ch<11>(xb, Wb, bias, acc[1]);
        do_ch<15>(xb, Wb, bias, acc[1]); do_ch<26>(xb, Wb, bias, acc[1]);
        do_ch<28>(xb, Wb, bias, acc[1]); do_ch<29>(xb, Wb, bias, acc[1]);
        store_g(ob, 5, 1.f/16, acc[0], lane);
        store_g(ob, 8, 1.f/48, acc[1], lane);
        break;
    }
}

extern "C" void kernel_launch(void* const* d_in, const int* in_sizes, int n_in,
                              void* d_out, int out_size, void* d_ws, size_t ws_size,
                              hipStream_t stream) {
    const float* x    = (const float*)d_in[0];
    const float* W    = (const float*)d_in[1];
    const float* bias = (const float*)d_in[2];
    float* out        = (float*)d_out;

    const int grid = NB * NTB;   // 512 * 8 = 4096 blocks
    hipLaunchKernelGGL(local_gnn_kernel, dim3(grid), dim3(256), 0, stream,
                       x, W, bias, out);
}